// Round 10
// baseline (477.964 us; speedup 1.0000x reference)
//
#include <hip/hip_runtime.h>
#include <math.h>
#include <stdint.h>

// Problem constants
#define B_   128
#define IN_  1024
#define OUT_ 1024
#define E_   32

// moe_main tiling
#define SLAB  32                 // i-rows per block
#define NSLAB (IN_ / SLAB)       // 32
#define CHR   4                  // rows per DMA chunk (16 KB)
#define NCH   (SLAB / CHR)       // 8
#define S_    16                 // samples per group pass
#define THR   512

// async global->LDS copy, 16 B per lane (dest = wave-uniform base + lane*16,
// which our linear unit indexing satisfies: unit = j*512 + t)
#define ASYNC16(gp, lp)                                                        \
  __builtin_amdgcn_global_load_lds(                                            \
      (__attribute__((address_space(1))) void*)(gp),                           \
      (__attribute__((address_space(3))) void*)(lp), 16, 0, 0)

// ---------------- Kernel A: routing, one block per (sample, router) --------------
// route layout: route[(b*2 + r)*4] = [idx0, idx1, p0, p1]  (idx bit-cast)
// r==1 blocks additionally write out[b] = pb0*eb[ib0] + pb1*eb[ib1] (bias init).
__global__ __launch_bounds__(256) void route_kernel(
    const float* __restrict__ x, const float* __restrict__ rw,
    const float* __restrict__ brw, const float* __restrict__ eb,
    float* __restrict__ route, float* __restrict__ out) {
  int b = blockIdx.x;
  int r = blockIdx.y;
  int t = threadIdx.x;
  const float* w = r ? brw : rw;

  __shared__ float xs[IN_];
  __shared__ float part[8][E_];
  __shared__ float lg[E_];
  __shared__ float res[4];

  ((float4*)xs)[t] = ((const float4*)(x + (size_t)b * IN_))[t];
  __syncthreads();

  int e  = t & 31;
  int ic = t >> 5;
  int base = ic * 128;
  float acc = 0.f;
  #pragma unroll 8
  for (int i = 0; i < 128; ++i)
    acc += xs[base + i] * w[(size_t)(base + i) * E_ + e];
  part[ic][e] = acc;
  __syncthreads();

  if (t < E_) {
    float s = 0.f;
    #pragma unroll
    for (int q = 0; q < 8; ++q) s += part[q][t];
    lg[t] = s;
  }
  __syncthreads();

  if (t == 0) {
    int bi0 = -1, bi1 = -1;
    float v0 = -INFINITY, v1 = -INFINITY;
    for (int ee = 0; ee < E_; ++ee) {
      float v = lg[ee];
      if (v > v0) { v1 = v0; bi1 = bi0; v0 = v; bi0 = ee; }
      else if (v > v1) { v1 = v; bi1 = ee; }
    }
    float p0 = 1.f / (1.f + expf(v1 - v0));
    float* rp = route + ((size_t)b * 2 + r) * 4;
    rp[0] = __int_as_float(bi0);
    rp[1] = __int_as_float(bi1);
    rp[2] = p0;
    rp[3] = 1.f - p0;
    res[0] = __int_as_float(bi0);
    res[1] = __int_as_float(bi1);
    res[2] = p0;
    res[3] = 1.f - p0;
  }

  if (r == 1) {
    __syncthreads();
    int ib0 = __float_as_int(res[0]);
    int ib1 = __float_as_int(res[1]);
    float pb0 = res[2], pb1 = res[3];
    float4 b0 = ((const float4*)(eb + (size_t)ib0 * OUT_))[t];
    float4 b1 = ((const float4*)(eb + (size_t)ib1 * OUT_))[t];
    float4 o;
    o.x = pb0 * b0.x + pb1 * b1.x;
    o.y = pb0 * b0.y + pb1 * b1.y;
    o.z = pb0 * b0.z + pb1 * b1.z;
    o.w = pb0 * b0.w + pb1 * b1.w;
    ((float4*)(out + (size_t)b * OUT_))[t] = o;
  }
}

// ---------------- Kernel B: grouped expert matvecs, async-DMA pipelined ----------
// block = (e, slab of 32 rows). Weight slab (128 KB) streamed linearly through a
// double-buffered LDS tile via global_load_lds (16 KB chunks, fire-and-forget
// DMA: no VGPR dependency, outstanding bytes guaranteed between issue and the
// barrier). Per-expert sample list built in-block from route (hidden under
// chunk-0's DMA flight). Thread t owns output cols [2t,2t+1]; acc float2[16]
// fully static. One atomic contribution per (sample, col pair, slab).
__global__ __launch_bounds__(THR) void moe_main(
    const float* __restrict__ x, const float* __restrict__ ew,
    const float* __restrict__ route, float* __restrict__ out) {
  int e    = blockIdx.x;
  int slab = blockIdx.y;

  __shared__ float  wbuf[2][CHR * OUT_];   // 2 x 16 KB
  __shared__ float  xs[SLAB][S_];          // 2 KB, [i][s], rows 64B-aligned
  __shared__ float4 rsh[B_];               // 2 KB route cache
  __shared__ int    ls_b[B_];
  __shared__ float  ls_p[B_];
  __shared__ int    cnt_sh;

  int t = threadIdx.x;
  const float* wslab = ew + ((size_t)e * IN_ + (size_t)slab * SLAB) * OUT_;

  // issue chunk 0 DMA immediately (independent of routing)
  {
    const float* src = wslab;
    float* dst = wbuf[0];
    #pragma unroll
    for (int j = 0; j < (CHR * OUT_) / (4 * THR); ++j) {
      int unit = j * THR + t;
      ASYNC16(src + unit * 4, dst + unit * 4);
    }
  }

  // route cache + per-expert list scan (overlaps chunk-0 DMA)
  if (t < B_) rsh[t] = *(const float4*)(route + (size_t)t * 8);
  __syncthreads();
  if (t == 0) {
    int c = 0;
    for (int b = 0; b < B_; ++b) {
      float4 r = rsh[b];
      if (__float_as_int(r.x) == e)      { ls_b[c] = b; ls_p[c] = r.z; ++c; }
      else if (__float_as_int(r.y) == e) { ls_b[c] = b; ls_p[c] = r.w; ++c; }
    }
    cnt_sh = c;
  }
  __syncthreads();
  int c = cnt_sh;
  if (c == 0) return;

  for (int g0 = 0; g0 < c; g0 += S_) {
    // restage chunk 0 for later passes (buffer cycled)
    if (g0 > 0) {
      const float* src = wslab;
      float* dst = wbuf[0];
      #pragma unroll
      for (int j = 0; j < (CHR * OUT_) / (4 * THR); ++j) {
        int unit = j * THR + t;
        ASYNC16(src + unit * 4, dst + unit * 4);
      }
    }

    // stage x transposed: thread t -> (s = t&15, i = t>>4)
    {
      int s  = t & 15;
      int ii = t >> 4;                    // 0..31
      int idx = min(g0 + s, c - 1);
      xs[ii][s] = x[(size_t)ls_b[idx] * IN_ + (size_t)slab * SLAB + ii];
    }

    // issue chunk 1 DMA
    {
      const float* src = wslab + (size_t)CHR * OUT_;
      float* dst = wbuf[1];
      #pragma unroll
      for (int j = 0; j < (CHR * OUT_) / (4 * THR); ++j) {
        int unit = j * THR + t;
        ASYNC16(src + unit * 4, dst + unit * 4);
      }
    }
    __syncthreads();   // chunk0 + xs ready (chunk1 drained too; same stream)

    float2 acc[S_];
    #pragma unroll
    for (int s = 0; s < S_; ++s) acc[s] = make_float2(0.f, 0.f);

    #pragma unroll
    for (int ch = 0; ch < NCH; ++ch) {
      // stage chunk ch+1 (for ch>=1; overlaps this chunk's compute)
      if (ch >= 1 && ch + 1 < NCH) {
        const float* src = wslab + (size_t)(ch + 1) * CHR * OUT_;
        float* dst = wbuf[(ch + 1) & 1];
        #pragma unroll
        for (int j = 0; j < (CHR * OUT_) / (4 * THR); ++j) {
          int unit = j * THR + t;
          ASYNC16(src + unit * 4, dst + unit * 4);
        }
      }

      // compute chunk ch from LDS
      const float* wl = wbuf[ch & 1];
      #pragma unroll
      for (int r = 0; r < CHR; ++r) {
        int row = ch * CHR + r;
        float2 wv = *(const float2*)(wl + r * OUT_ + 2 * t);
        const float4* xr = (const float4*)xs[row];
        float4 xa = xr[0], xb = xr[1], xc = xr[2], xd = xr[3];
        acc[0].x  += xa.x * wv.x;  acc[0].y  += xa.x * wv.y;
        acc[1].x  += xa.y * wv.x;  acc[1].y  += xa.y * wv.y;
        acc[2].x  += xa.z * wv.x;  acc[2].y  += xa.z * wv.y;
        acc[3].x  += xa.w * wv.x;  acc[3].y  += xa.w * wv.y;
        acc[4].x  += xb.x * wv.x;  acc[4].y  += xb.x * wv.y;
        acc[5].x  += xb.y * wv.x;  acc[5].y  += xb.y * wv.y;
        acc[6].x  += xb.z * wv.x;  acc[6].y  += xb.z * wv.y;
        acc[7].x  += xb.w * wv.x;  acc[7].y  += xb.w * wv.y;
        acc[8].x  += xc.x * wv.x;  acc[8].y  += xc.x * wv.y;
        acc[9].x  += xc.y * wv.x;  acc[9].y  += xc.y * wv.y;
        acc[10].x += xc.z * wv.x;  acc[10].y += xc.z * wv.y;
        acc[11].x += xc.w * wv.x;  acc[11].y += xc.w * wv.y;
        acc[12].x += xd.x * wv.x;  acc[12].y += xd.x * wv.y;
        acc[13].x += xd.y * wv.x;  acc[13].y += xd.y * wv.y;
        acc[14].x += xd.z * wv.x;  acc[14].y += xd.z * wv.y;
        acc[15].x += xd.w * wv.x;  acc[15].y += xd.w * wv.y;
      }
      __syncthreads();   // next chunk's DMA drained; buffers swap safely
    }

    // epilogue: one atomic contribution per (sample, col pair) for this slab
    #pragma unroll
    for (int s = 0; s < S_; ++s) {
      int idx = g0 + s;
      if (idx < c) {
        float p = ls_p[idx];
        float* op = out + (size_t)ls_b[idx] * OUT_ + 2 * t;
        atomicAdd(op + 0, p * acc[s].x);
        atomicAdd(op + 1, p * acc[s].y);
      }
    }
  }
}

extern "C" void kernel_launch(void* const* d_in, const int* in_sizes, int n_in,
                              void* d_out, int out_size, void* d_ws, size_t ws_size,
                              hipStream_t stream) {
  const float* x   = (const float*)d_in[0];
  const float* rw  = (const float*)d_in[1];
  const float* brw = (const float*)d_in[2];
  const float* ew  = (const float*)d_in[3];
  const float* eb  = (const float*)d_in[4];
  float* out = (float*)d_out;

  float* route = (float*)d_ws;   // 128*2*4 floats = 4 KB

  route_kernel<<<dim3(B_, 2), 256, 0, stream>>>(x, rw, brw, eb, route, out);
  moe_main<<<dim3(E_, NSLAB), THR, 0, stream>>>(x, ew, route, out);
}

// Round 11
// 70.472 us; speedup vs baseline: 6.7823x; 6.7823x over previous
//
#include <hip/hip_runtime.h>
#include <math.h>

// Problem constants
#define B_   128
#define IN_  1024
#define OUT_ 1024
#define E_   32

// moe_main tiling
#define SLAB  64                 // i-rows per block
#define NSLAB (IN_ / SLAB)       // 16
#define S_    16                 // samples per group pass
#define RB    4                  // rows per prefetch batch (known-good, no spill)
#define THR   512

// ws layout (bytes)
#define WS_ROUTE   0
#define WS_COUNTS  4096
#define WS_LISTB   8192
#define WS_LISTK   24576
#define WS_LISTP   40960
#define WS_PART    65536          // 2*NSLAB*B_*OUT_ floats = 16 MB

// ---------------- Kernel A: routing, one block per (sample, router) --------------
// route layout: route[(b*2 + r)*4] = [idx0, idx1, p0, p1]  (idx bit-cast)
// r==1 blocks additionally write out[b] = pb0*eb[ib0] + pb1*eb[ib1] (bias init).
__global__ __launch_bounds__(256) void route_kernel(
    const float* __restrict__ x, const float* __restrict__ rw,
    const float* __restrict__ brw, const float* __restrict__ eb,
    float* __restrict__ route, float* __restrict__ out) {
  int b = blockIdx.x;
  int r = blockIdx.y;
  int t = threadIdx.x;
  const float* w = r ? brw : rw;

  __shared__ float xs[IN_];
  __shared__ float part[8][E_];
  __shared__ float lg[E_];
  __shared__ float res[4];

  ((float4*)xs)[t] = ((const float4*)(x + (size_t)b * IN_))[t];
  __syncthreads();

  int e  = t & 31;
  int ic = t >> 5;
  int base = ic * 128;
  float acc = 0.f;
  #pragma unroll 8
  for (int i = 0; i < 128; ++i)
    acc += xs[base + i] * w[(size_t)(base + i) * E_ + e];
  part[ic][e] = acc;
  __syncthreads();

  if (t < E_) {
    float s = 0.f;
    #pragma unroll
    for (int q = 0; q < 8; ++q) s += part[q][t];
    lg[t] = s;
  }
  __syncthreads();

  if (t == 0) {
    int bi0 = -1, bi1 = -1;
    float v0 = -INFINITY, v1 = -INFINITY;
    for (int ee = 0; ee < E_; ++ee) {
      float v = lg[ee];
      if (v > v0) { v1 = v0; bi1 = bi0; v0 = v; bi0 = ee; }
      else if (v > v1) { v1 = v; bi1 = ee; }
    }
    float p0 = 1.f / (1.f + expf(v1 - v0));
    float* rp = route + ((size_t)b * 2 + r) * 4;
    rp[0] = __int_as_float(bi0);
    rp[1] = __int_as_float(bi1);
    rp[2] = p0;
    rp[3] = 1.f - p0;
    res[0] = __int_as_float(bi0);
    res[1] = __int_as_float(bi1);
    res[2] = p0;
    res[3] = 1.f - p0;
  }

  if (r == 1) {
    __syncthreads();
    int ib0 = __float_as_int(res[0]);
    int ib1 = __float_as_int(res[1]);
    float pb0 = res[2], pb1 = res[3];
    float4 b0 = ((const float4*)(eb + (size_t)ib0 * OUT_))[t];
    float4 b1 = ((const float4*)(eb + (size_t)ib1 * OUT_))[t];
    float4 o;
    o.x = pb0 * b0.x + pb1 * b1.x;
    o.y = pb0 * b0.y + pb1 * b1.y;
    o.z = pb0 * b0.z + pb1 * b1.z;
    o.w = pb0 * b0.w + pb1 * b1.w;
    ((float4*)(out + (size_t)b * OUT_))[t] = o;
  }
}

// ---------------- Kernel A2: per-expert sample lists (deterministic scan) --------
// Also records k: whether this expert is the sample's top-1 (k=0) or top-2 (k=1).
__global__ __launch_bounds__(128) void build_lists(
    const float* __restrict__ route, int* __restrict__ counts,
    int* __restrict__ list_b, int* __restrict__ list_k,
    float* __restrict__ list_p) {
  __shared__ float4 r_sh[B_];
  int t = threadIdx.x;  // 128
  r_sh[t] = *(const float4*)(route + (size_t)t * 8);  // router-0 entry of sample t
  __syncthreads();
  if (t < E_) {
    int c = 0;
    for (int b = 0; b < B_; ++b) {
      float4 r = r_sh[b];
      int i0 = __float_as_int(r.x);
      int i1 = __float_as_int(r.y);
      if (i0 == t)      { list_b[t*B_ + c] = b; list_k[t*B_ + c] = 0; list_p[t*B_ + c] = r.z; ++c; }
      else if (i1 == t) { list_b[t*B_ + c] = b; list_k[t*B_ + c] = 1; list_p[t*B_ + c] = r.w; ++c; }
    }
    counts[t] = c;
  }
}

// ---------------- Kernel C: linear-streamed expert matvecs, ATOMIC-FREE ----------
// block = (e, slab of 64 i-rows); 512 threads: thread t owns output cols
// [2t, 2t+1], directly consuming its own coalesced weight loads (block-level
// linear stream: 8 waves jointly cover each 4 KB row). RB=4 rows
// double-buffered in registers (known-good, no spill). Slab partials go to a
// DISJOINT ws slot part[k][slab][b][col] via plain stores (exactly one writer
// per slot -> deterministic, zero atomics).
__global__ __launch_bounds__(THR) void moe_main(
    const float* __restrict__ x, const float* __restrict__ ew,
    const int* __restrict__ counts, const int* __restrict__ list_b,
    const int* __restrict__ list_k, const float* __restrict__ list_p,
    float* __restrict__ part) {
  int e    = blockIdx.x;
  int slab = blockIdx.y;
  int c = counts[e];
  if (c == 0) return;

  __shared__ float xs[SLAB][S_];   // [i][s], rows 64B-aligned -> b128 broadcast reads
  __shared__ int   bs[S_];
  __shared__ int   ks[S_];
  __shared__ float ps[S_];

  int t  = threadIdx.x;
  int i0 = slab * SLAB;
  const float* wslab = ew + ((size_t)e * IN_ + i0) * OUT_;

  for (int g0 = 0; g0 < c; g0 += S_) {
    __syncthreads();   // previous pass's readers done
    if (t < S_) {
      int idx = g0 + t;
      int cidx = min(idx, c - 1);
      bs[t] = list_b[e * B_ + cidx];
      ks[t] = list_k[e * B_ + cidx];
      ps[t] = (idx < c) ? list_p[e * B_ + cidx] : 0.f;
    }
    __syncthreads();

    // stage x transposed: thread t -> (s = t&15, row pair 2*(t>>4)), float2
    {
      int s  = t & 15;
      int ip = t >> 4;                    // 0..31
      const float* xr = x + (size_t)bs[s] * IN_ + i0 + 2 * ip;
      float2 v = *(const float2*)xr;
      xs[2 * ip][s]     = v.x;
      xs[2 * ip + 1][s] = v.y;
    }
    __syncthreads();

    float2 acc[S_];
    #pragma unroll
    for (int s = 0; s < S_; ++s) acc[s] = make_float2(0.f, 0.f);

    // prologue: load batch 0 (4 independent dwordx2)
    float2 cur[RB];
    {
      const float* wp = wslab + 2 * t;
      #pragma unroll
      for (int r = 0; r < RB; ++r)
        cur[r] = *(const float2*)(wp + (size_t)r * OUT_);
    }

    #pragma unroll 2
    for (int ib = 0; ib < SLAB; ib += RB) {
      bool has_next = (ib + RB < SLAB);
      float2 nxt[RB];
      if (has_next) {
        const float* wp = wslab + (size_t)(ib + RB) * OUT_ + 2 * t;
        #pragma unroll
        for (int r = 0; r < RB; ++r)
          nxt[r] = *(const float2*)(wp + (size_t)r * OUT_);
      }

      #pragma unroll
      for (int r = 0; r < RB; ++r) {
        const float4* xr = (const float4*)xs[ib + r];
        float4 xa = xr[0], xb = xr[1], xc = xr[2], xd = xr[3];
        float2 wv = cur[r];
        acc[0].x  += xa.x * wv.x;  acc[0].y  += xa.x * wv.y;
        acc[1].x  += xa.y * wv.x;  acc[1].y  += xa.y * wv.y;
        acc[2].x  += xa.z * wv.x;  acc[2].y  += xa.z * wv.y;
        acc[3].x  += xa.w * wv.x;  acc[3].y  += xa.w * wv.y;
        acc[4].x  += xb.x * wv.x;  acc[4].y  += xb.x * wv.y;
        acc[5].x  += xb.y * wv.x;  acc[5].y  += xb.y * wv.y;
        acc[6].x  += xb.z * wv.x;  acc[6].y  += xb.z * wv.y;
        acc[7].x  += xb.w * wv.x;  acc[7].y  += xb.w * wv.y;
        acc[8].x  += xc.x * wv.x;  acc[8].y  += xc.x * wv.y;
        acc[9].x  += xc.y * wv.x;  acc[9].y  += xc.y * wv.y;
        acc[10].x += xc.z * wv.x;  acc[10].y += xc.z * wv.y;
        acc[11].x += xc.w * wv.x;  acc[11].y += xc.w * wv.y;
        acc[12].x += xd.x * wv.x;  acc[12].y += xd.x * wv.y;
        acc[13].x += xd.y * wv.x;  acc[13].y += xd.y * wv.y;
        acc[14].x += xd.z * wv.x;  acc[14].y += xd.z * wv.y;
        acc[15].x += xd.w * wv.x;  acc[15].y += xd.w * wv.y;
      }

      if (has_next) {
        #pragma unroll
        for (int r = 0; r < RB; ++r) cur[r] = nxt[r];
      }
    }

    // epilogue: plain store into the disjoint partial slot (p applied here).
    // Guarded: pad slots would alias sample c-1's slot with p=0.
    #pragma unroll
    for (int s = 0; s < S_; ++s) {
      if (g0 + s < c) {
        float p = ps[s];
        float* op = part + (((size_t)ks[s] * NSLAB + slab) * B_ + bs[s]) * OUT_ + 2 * t;
        op[0] = p * acc[s].x;
        op[1] = p * acc[s].y;
      }
    }
  }
}

// ---------------- Kernel D: reduce partials into out ----------------
// out[b][col] = bias(already in out) + sum_{k,slab} part[k][slab][b][col].
// One thread per 4 cols; 32 independent float4 loads, no atomics.
__global__ __launch_bounds__(256) void reduce_kernel(
    const float* __restrict__ part, float* __restrict__ out) {
  int b = blockIdx.x;
  int t = threadIdx.x;                 // 256, col = 4t
  float4 a = ((const float4*)(out + (size_t)b * OUT_))[t];
  #pragma unroll
  for (int k = 0; k < 2; ++k) {
    #pragma unroll
    for (int sl = 0; sl < NSLAB; ++sl) {
      float4 v = ((const float4*)(part + (((size_t)k * NSLAB + sl) * B_ + b) * OUT_))[t];
      a.x += v.x; a.y += v.y; a.z += v.z; a.w += v.w;
    }
  }
  ((float4*)(out + (size_t)b * OUT_))[t] = a;
}

extern "C" void kernel_launch(void* const* d_in, const int* in_sizes, int n_in,
                              void* d_out, int out_size, void* d_ws, size_t ws_size,
                              hipStream_t stream) {
  const float* x   = (const float*)d_in[0];
  const float* rw  = (const float*)d_in[1];
  const float* brw = (const float*)d_in[2];
  const float* ew  = (const float*)d_in[3];
  const float* eb  = (const float*)d_in[4];
  float* out = (float*)d_out;

  char* ws = (char*)d_ws;
  float* route  = (float*)(ws + WS_ROUTE);
  int*   counts = (int*)(ws + WS_COUNTS);
  int*   list_b = (int*)(ws + WS_LISTB);
  int*   list_k = (int*)(ws + WS_LISTK);
  float* list_p = (float*)(ws + WS_LISTP);
  float* part   = (float*)(ws + WS_PART);   // 2*NSLAB*B_*OUT_ floats = 16 MB

  route_kernel<<<dim3(B_, 2), 256, 0, stream>>>(x, rw, brw, eb, route, out);
  build_lists<<<1, 128, 0, stream>>>(route, counts, list_b, list_k, list_p);
  moe_main<<<dim3(E_, NSLAB), THR, 0, stream>>>(x, ew, counts, list_b, list_k, list_p, part);
  reduce_kernel<<<B_, 256, 0, stream>>>(part, out);
}